// Round 1
// 162.377 us; speedup vs baseline: 1.0154x; 1.0154x over previous
//
#include <hip/hip_runtime.h>
#include <hip/hip_bf16.h>
#include <math.h>

#define NCLS 256
#define PER_CLASS 128
#define NSUP 5
#define NQRY 123              // PER_CLASS - NSUP
#define NVIEW 2
#define DD 384
#define NQ_TOT (NCLS * NQRY)  // 31488
#define BM 128                // queries per block
#define BK 32                 // k-tile (elems)
#define NKT (DD / BK)         // 12
#define QS 40                 // Q LDS row stride in ushorts (16B-aligned; uniform-slot = conflict-free)
#define PS 32                 // P LDS row stride in ushorts (unpadded: global_load_lds writes linearly)

typedef __attribute__((ext_vector_type(8))) short short8;
typedef __attribute__((ext_vector_type(4))) float floatx4;

union FragU { uint4 u; short8 s; };
union PkU { __hip_bfloat162 b2; unsigned int u; };

__device__ __forceinline__ unsigned int cvt2bf(float lo, float hi) {
    PkU p;
    p.b2 = __float22bfloat162_rn(make_float2(lo, hi));
    return p.u;
}

// async global->LDS, 16B per lane; LDS dest is wave-uniform base + lane*16 (HW rule)
__device__ __forceinline__ void gll16(const ushort* g, ushort* l) {
    __builtin_amdgcn_global_load_lds(
        (const __attribute__((address_space(1))) unsigned int*)g,
        (__attribute__((address_space(3))) unsigned int*)l, 16, 0, 0);
}

// barrier WITHOUT the vmcnt(0) drain __syncthreads would emit:
// LDS writes visible (lgkmcnt(0)), in-flight global/gll loads keep flying.
#define BARRIER() asm volatile("s_waitcnt lgkmcnt(0)\n\ts_barrier" ::: "memory")
#define WAITVM(n) asm volatile("s_waitcnt vmcnt(" #n ")" ::: "memory")

// ---------- kernel 1: prototypes -> bf16 + y2 + out-zero, fused ----------
__global__ __launch_bounds__(384) void proto_kernel(const float* __restrict__ reps,
                                                    ushort* __restrict__ pbf,
                                                    float* __restrict__ y2,
                                                    float* __restrict__ out) {
    __shared__ float wp[6];
    const int b = blockIdx.x;          // v*256 + c
    const int c = b & 255, v = b >> 8;
    const int d = threadIdx.x;         // 0..383
    if (b == 0 && d == 0) out[0] = 0.f;   // replaces the hipMemsetAsync dispatch
    const float* p = reps + ((size_t)(c * PER_CLASS) * NVIEW + v) * DD + d;
    float s = 0.f;
#pragma unroll
    for (int k = 0; k < NSUP; ++k) s += p[(size_t)k * NVIEW * DD];
    s *= 0.2f;
    __hip_bfloat16 h = __float2bfloat16(s);
    pbf[(size_t)b * DD + d] = *reinterpret_cast<ushort*>(&h);
    float q = s * s;
#pragma unroll
    for (int o = 1; o < 64; o <<= 1) q += __shfl_xor(q, o);
    if ((d & 63) == 0) wp[d >> 6] = q;
    __syncthreads();
    if (d == 0) y2[b] = wp[0] + wp[1] + wp[2] + wp[3] + wp[4] + wp[5];
}

// ---------- kernel 2: bf16 MFMA GEMM + fused logsumexp/NLL ----------
// P operand staged by global_load_lds (async, no VGPR round-trip, no ds_writes).
// 2-tile lookahead, counted vmcnt(8) in steady state (never drain to 0 mid-loop).
__global__ __launch_bounds__(256, 2) void main_kernel(const float* __restrict__ reps,
                                                      const ushort* __restrict__ pbf,
                                                      const float* __restrict__ y2g,
                                                      float* __restrict__ out) {
    __shared__ ushort q_lds[2][BM * QS];    // 2 x 10240 B
    __shared__ ushort p_lds[2][NCLS * PS];  // 2 x 16384 B
    __shared__ float pmx[BM][2];
    __shared__ float pse[BM][2];
    __shared__ float wred[8];

    const int t = threadIdx.x;
    const int v = blockIdx.y;
    const int q0 = blockIdx.x * BM;
    const int wave = t >> 6;
    const int lane = t & 63;
    const int col = lane & 15;   // MFMA m/n index
    const int quad = lane >> 4;  // MFMA k-chunk / C row group
    const int wm = wave >> 1;    // query half
    const int wn = wave & 1;     // class half

    // Q staging map: 2 threads/row (t>>1 = row, (t&1)*16 = float offset)
    const int sq = t >> 1;
    const int h16 = (t & 1) * 16;
    const int nq = q0 + sq;
    const float* qsrc = reps +
        (size_t)((nq / NQRY) * PER_CLASS + NSUP + (nq % NQRY)) * (NVIEW * DD) + v * DD + h16;

    // P gll map: wave w stages rows 64w..64w+63; call i covers rows 64w+16i..+15.
    // lane l -> LDS row 64w+16i+(l>>2), phys chunk (l&3).  Source is chunk-XOR-swizzled so
    // phys chunk c holds data chunk c ^ ((row>>1)&3); reads at phys = quad ^ ((col>>1)&3)
    // then occupy all 8 16B-slots uniformly (conflict-free despite the unpadded stride).
    const ushort* psrc = pbf + (size_t)(v * NCLS + wave * 64 + (lane >> 2)) * DD
                             + (((lane & 3) ^ ((lane >> 3) & 3)) << 3);

    const int sP = (col >> 1) & 3;
    int boff[8];
#pragma unroll
    for (int nt = 0; nt < 8; ++nt)
        boff[nt] = (wn * 128 + nt * 16 + col) * PS + ((quad ^ sP) << 3);

    floatx4 acc[4][8];
#pragma unroll
    for (int mt = 0; mt < 4; ++mt)
#pragma unroll
        for (int nt = 0; nt < 8; ++nt) acc[mt][nt] = (floatx4)0.f;

    float4 qfA[4], qfB[4];

#define LOADQ(kt, R)                                                               \
    do {                                                                           \
        _Pragma("unroll") for (int i = 0; i < 4; ++i)                              \
            R[i] = *(const float4*)(qsrc + (kt) * BK + i * 4);                     \
    } while (0)

#define GLLP(kt, b)                                                                \
    do {                                                                           \
        _Pragma("unroll") for (int i = 0; i < 4; ++i)                              \
            gll16(psrc + i * (16 * DD) + (kt) * BK,                                \
                  &p_lds[b][wave * 2048 + i * 512]);                               \
    } while (0)

#define STAGEQ(b, R)                                                               \
    do {                                                                           \
        uint4 w0, w1;                                                              \
        w0.x = cvt2bf(R[0].x, R[0].y); w0.y = cvt2bf(R[0].z, R[0].w);              \
        w0.z = cvt2bf(R[1].x, R[1].y); w0.w = cvt2bf(R[1].z, R[1].w);              \
        w1.x = cvt2bf(R[2].x, R[2].y); w1.y = cvt2bf(R[2].z, R[2].w);              \
        w1.z = cvt2bf(R[3].x, R[3].y); w1.w = cvt2bf(R[3].z, R[3].w);              \
        *(uint4*)&q_lds[b][sq * QS + h16] = w0;                                    \
        *(uint4*)&q_lds[b][sq * QS + h16 + 8] = w1;                                \
    } while (0)

#define COMPUTE(b)                                                                 \
    do {                                                                           \
        short8 af[4];                                                              \
        _Pragma("unroll") for (int mt = 0; mt < 4; ++mt) {                         \
            FragU f;                                                               \
            f.u = *(const uint4*)&q_lds[b][(wm * 64 + mt * 16 + col) * QS + quad * 8]; \
            af[mt] = f.s;                                                          \
        }                                                                          \
        _Pragma("unroll") for (int nt = 0; nt < 8; ++nt) {                         \
            FragU bb;                                                              \
            bb.u = *(const uint4*)&p_lds[b][boff[nt]];                             \
            _Pragma("unroll") for (int mt = 0; mt < 4; ++mt)                       \
                acc[mt][nt] = __builtin_amdgcn_mfma_f32_16x16x32_bf16(af[mt], bb.s, acc[mt][nt], 0, 0, 0); \
        }                                                                          \
    } while (0)

    // ---- prologue: tiles 0 and 1 in flight (FIFO: Q0,P0,Q1,P1) ----
    LOADQ(0, qfA); GLLP(0, 0);
    LOADQ(1, qfB); GLLP(1, 1);
    WAITVM(8);          // Q0 regs + P0 LDS done; tile-1 ops (8) still flying
    STAGEQ(0, qfA);
    BARRIER();          // tile 0 ready

#pragma unroll
    for (int kt = 0; kt < NKT; ++kt) {
        COMPUTE(kt & 1);
        if (kt == NKT - 1) break;
        BARRIER();      // all waves done reading buf kt&1 -> safe to gll into it
        if (kt + 2 < NKT) {
            if ((kt & 1) == 0) { LOADQ(kt + 2, qfA); } else { LOADQ(kt + 2, qfB); }
            GLLP(kt + 2, kt & 1);
            WAITVM(8);  // drains tile kt+1's 8 ops; tile kt+2's 8 stay in flight
        } else {
            WAITVM(0);  // last tile: nothing newer outstanding
        }
        if ((kt & 1) == 0) STAGEQ(1, qfB); else STAGEQ(0, qfA);
        BARRIER();      // tile kt+1 ready (each wave vmcnt-waited its gll before this)
    }

    // ---- epilogue (identical to verified r2) ----
    float y2c[8];
#pragma unroll
    for (int nt = 0; nt < 8; ++nt) y2c[nt] = y2g[v * NCLS + wn * 128 + nt * 16 + col];

    float corr = 0.f;
#pragma unroll
    for (int mt = 0; mt < 4; ++mt) {
#pragma unroll
        for (int r = 0; r < 4; ++r) {
            const int qloc = wm * 64 + mt * 16 + quad * 4 + r;
            const int n = q0 + qloc;
            const int cn = n / NQRY;
            float s[8];
            float mx = -1e30f;
#pragma unroll
            for (int nt = 0; nt < 8; ++nt) {
                s[nt] = 2.f * acc[mt][nt][r] - y2c[nt];
                mx = fmaxf(mx, s[nt]);
                if (cn == wn * 128 + nt * 16 + col) corr += s[nt];
            }
#pragma unroll
            for (int o = 1; o < 16; o <<= 1) mx = fmaxf(mx, __shfl_xor(mx, o));
            float e = 0.f;
#pragma unroll
            for (int nt = 0; nt < 8; ++nt) e += __expf(s[nt] - mx);
#pragma unroll
            for (int o = 1; o < 16; o <<= 1) e += __shfl_xor(e, o);
            if (col == 0) { pmx[qloc][wn] = mx; pse[qloc][wn] = e; }
        }
    }
#pragma unroll
    for (int o = 1; o < 64; o <<= 1) corr += __shfl_xor(corr, o);
    if (lane == 0) wred[wave] = corr;
    __syncthreads();

    float lval = 0.f;
    if (t < BM) {
        float m0 = pmx[t][0], m1 = pmx[t][1];
        float M = fmaxf(m0, m1);
        float E = pse[t][0] * __expf(m0 - M) + pse[t][1] * __expf(m1 - M);
        lval = M + __logf(E);
    }
#pragma unroll
    for (int o = 1; o < 64; o <<= 1) lval += __shfl_xor(lval, o);
    if (lane == 0) wred[4 + wave] = lval;
    __syncthreads();

    if (t == 0) {
        float tot = (wred[4] + wred[5] + wred[6] + wred[7]) -
                    (wred[0] + wred[1] + wred[2] + wred[3]);
        atomicAdd(out, tot * (1.f / (float)(NQ_TOT * NVIEW)));
    }
}

extern "C" void kernel_launch(void* const* d_in, const int* in_sizes, int n_in,
                              void* d_out, int out_size, void* d_ws, size_t ws_size,
                              hipStream_t stream) {
    const float* reps = (const float*)d_in[0];
    float* ws = (float*)d_ws;
    ushort* pbf = (ushort*)ws;                      // 196608 ushorts
    float* y2 = (float*)(pbf + NVIEW * NCLS * DD);  // 512 floats
    float* out = (float*)d_out;

    proto_kernel<<<dim3(NVIEW * NCLS), dim3(DD), 0, stream>>>(reps, pbf, y2, out);
    main_kernel<<<dim3(NQ_TOT / BM, NVIEW), dim3(256), 0, stream>>>(reps, pbf, y2, out);
}